// Round 3
// baseline (109.489 us; speedup 1.0000x reference)
//
#include <hip/hip_runtime.h>
#include <hip/hip_bf16.h>

// pointconv fused: density MLP + weight-net + per-point [64x32]x[32x32] + [128x2048] GEMV + BN
// B=16 NP=1024 NS=32 CIN=64 CMID=32 COUT=128. Inputs f32, outputs f32 (bf16 MFMA inside).

#define NPP 1024
#define NSS 32

typedef __attribute__((ext_vector_type(8))) short short8;
typedef __attribute__((ext_vector_type(4))) float f32x4;

__device__ __forceinline__ unsigned short f2bf(float x) {
  union { float f; unsigned u; } v; v.f = x;
  unsigned r = v.u + 0x7FFFu + ((v.u >> 16) & 1u);   // RNE
  return (unsigned short)(r >> 16);
}

__device__ __forceinline__ unsigned long long pack4bf(f32x4 v) {
  return (unsigned long long)f2bf(v[0])
       | ((unsigned long long)f2bf(v[1]) << 16)
       | ((unsigned long long)f2bf(v[2]) << 32)
       | ((unsigned long long)f2bf(v[3]) << 48);
}

// ---- k_prep: OWb[o][kflat] bf16 (kflat = cblk*512 + k*16 + c_off) + output-0 transpose ----
__global__ __launch_bounds__(256) void k_prep(
    const float* __restrict__ out_w, const float* __restrict__ new_xyz,
    unsigned short* __restrict__ owb, float* __restrict__ out0)
{
  int bid = blockIdx.x, t = threadIdx.x;
  if (bid < 16) {
    int gk = bid * 256 + t;            // (o,k): o=gk>>5, k=gk&31 ; 128*32=4096
    int o = gk >> 5, k = gk & 31;
    #pragma unroll
    for (int cb = 0; cb < 4; ++cb) {
      short8 lo, hi;
      #pragma unroll
      for (int c = 0; c < 8; ++c) lo[c] = (short)f2bf(out_w[(o*64 + cb*16 + c)*32 + k]);
      #pragma unroll
      for (int c = 0; c < 8; ++c) hi[c] = (short)f2bf(out_w[(o*64 + cb*16 + 8 + c)*32 + k]);
      *(short8*)&owb[o*2048 + cb*512 + k*16]     = lo;
      *(short8*)&owb[o*2048 + cb*512 + k*16 + 8] = hi;
    }
  } else {
    int idx = (bid - 16) * 256 + t;    // < 49152
    int b = idx / 3072, r = idx - b*3072, p = r / 3, d = r - p*3;
    out0[idx] = new_xyz[(b*3 + d)*NPP + p];
  }
}

// ---- k_main: one wg = (b, 16-point tile), 4 waves, fused everything ----
struct Smem {
  unsigned short wd[16*32*32];   // [p][k][s] bf16 = 32768 B  (wd = w * d2)
  char mm[16*1040];              // [p][kflat-local] bf16, row = 1024B data + 16B pad
  float cst[192];                // folded BN consts
};

__global__ __launch_bounds__(256, 2) void k_main(
    const float* __restrict__ F, const float* __restrict__ GX,
    const float* __restrict__ whw, const float* __restrict__ whb,
    const float* __restrict__ whg, const float* __restrict__ whbeta,
    const float* __restrict__ whm, const float* __restrict__ whv,
    const float* __restrict__ n1w, const float* __restrict__ n1b,
    const float* __restrict__ n1g, const float* __restrict__ n1beta,
    const float* __restrict__ n1m, const float* __restrict__ n1v,
    const float* __restrict__ n2w, const float* __restrict__ n2b,
    const float* __restrict__ n2g, const float* __restrict__ n2beta,
    const float* __restrict__ n2m, const float* __restrict__ n2v,
    const unsigned short* __restrict__ OWb,
    const float* __restrict__ ob, const float* __restrict__ og,
    const float* __restrict__ obeta, const float* __restrict__ om,
    const float* __restrict__ ov,
    float* __restrict__ out1)
{
  __shared__ Smem sm;
  // XCD-aware bijective swizzle (1024 wgs % 8 == 0): consecutive work-tiles
  // share cache lines of F/GX; keep them on the same XCD.
  int bid = (blockIdx.x & 7) * 128 + (blockIdx.x >> 3);
  int b = bid >> 6, p0 = (bid & 63) << 4;
  int t = threadIdx.x, lane = t & 63, w = t >> 6;
  int l15 = lane & 15, sg = lane >> 4;

  // ---- phase 0a: gx load (s=0 zeroed per reference mutation), density->inv, max over s ----
  int pp = t >> 4, si = t & 15;        // pp = point 0..15, si -> s = 2si, 2si+1
  float gxl[2][3]; float invv[2];
  #pragma unroll
  for (int u = 0; u < 2; ++u) {
    int s = si*2 + u;
    float x = 0.f, y = 0.f, z = 0.f;
    if (s != 0) {
      const float* g = &GX[(size_t)((b*NPP + p0 + pp)*NSS + s)*3];
      x = g[0]; y = g[1]; z = g[2];
    }
    gxl[u][0]=x; gxl[u][1]=y; gxl[u][2]=z;
    float den = x + y + z;
    if (den < 1e-10f) den = 1e-10f;    // where(density < 1e-10, 1e-10, density)
    invv[u] = 1.0f / den;
  }
  float mx = fmaxf(invv[0], invv[1]);
  #pragma unroll
  for (int m = 1; m < 16; m <<= 1) mx = fmaxf(mx, __shfl_xor(mx, m, 16));

  // folded BN consts (wave 0 only -> no divergence elsewhere)
  if (t < 32) {
    float sc = whg[t] * rsqrtf(whv[t] + 1e-5f);
    sm.cst[t]    = whw[t*3+0] * sc;
    sm.cst[32+t] = whw[t*3+1] * sc;
    sm.cst[64+t] = whw[t*3+2] * sc;
    sm.cst[96+t] = (whb[t] - whm[t]) * sc + whbeta[t];
  } else if (t < 48) {
    int i = t - 32;
    float sc = n1g[i] * rsqrtf(n1v[i] + 1e-5f);
    sm.cst[128+i] = n1w[i] * sc;
    sm.cst[144+i] = (n1b[i] - n1m[i]) * sc + n1beta[i];
  } else if (t < 64) {
    int i = t - 48;
    float sc = n2g[0] * rsqrtf(n2v[0] + 1e-5f);
    sm.cst[160+i] = n2w[i] * sc;
    if (i == 0) sm.cst[176] = (n2b[0] - n2m[0]) * sc + n2beta[0];
  }
  __syncthreads();

  // ---- phase 0b: d2 = sigmoid(MLP(ds)), weight-net w, wd = w*d2 -> LDS ----
  float d2v[2];
  #pragma unroll
  for (int u = 0; u < 2; ++u) {
    float ds = invv[u] / mx;
    float acc = sm.cst[176];
    #pragma unroll
    for (int i = 0; i < 16; ++i) {
      float d1 = fmaxf(ds * sm.cst[128+i] + sm.cst[144+i], 0.f);
      acc += d1 * sm.cst[160+i];
    }
    d2v[u] = 1.0f / (1.0f + expf(-acc));
  }
  for (int k = 0; k < 32; ++k) {
    float a0 = sm.cst[k], a1 = sm.cst[32+k], a2 = sm.cst[64+k], bc = sm.cst[96+k];
    unsigned r = 0;
    #pragma unroll
    for (int u = 0; u < 2; ++u) {
      float wv = fmaxf(gxl[u][0]*a0 + gxl[u][1]*a1 + gxl[u][2]*a2 + bc, 0.f);
      wv *= d2v[u];
      r |= (unsigned)f2bf(wv) << (16*u);
    }
    *(unsigned*)&sm.wd[(pp*32 + k)*32 + si*2] = r;   // [p][k][s], s-pair packed
  }
  __syncthreads();

  // hoisted stage-1 B-frags (wd) for my wave's 4 points: B[k=s][n=k_out]
  int pl0 = w * 4;
  short8 bfr[4][2];
  #pragma unroll
  for (int i = 0; i < 4; ++i)
    #pragma unroll
    for (int kh = 0; kh < 2; ++kh)
      bfr[i][kh] = *(const short8*)&sm.wd[((pl0+i)*32 + kh*16 + l15)*32 + sg*8];

  f32x4 acc0 = {0,0,0,0}, acc1 = {0,0,0,0};
  const f32x4 z4 = {0,0,0,0};

  for (int cblk = 0; cblk < 4; ++cblk) {
    // ---- stage 1: mm[c,k] += F . wd  (one c-block, per-point MFMA) ----
    {
      // float4 over the wave's 4 consecutive points; lane: c = cblk*16+l15, s = sg*8+j
      const float* src = &F[(size_t)((b*64 + cblk*16 + l15)*32 + sg*8)*NPP + p0 + pl0];
      float4 av[8];
      #pragma unroll
      for (int j = 0; j < 8; ++j) av[j] = *(const float4*)&src[(size_t)j*NPP];
      short8 af[4];
      #pragma unroll
      for (int j = 0; j < 8; ++j) {
        af[0][j] = (short)f2bf(av[j].x);
        af[1][j] = (short)f2bf(av[j].y);
        af[2][j] = (short)f2bf(av[j].z);
        af[3][j] = (short)f2bf(av[j].w);
      }
      #pragma unroll
      for (int i = 0; i < 4; ++i) {
        f32x4 m0 = __builtin_amdgcn_mfma_f32_16x16x32_bf16(af[i], bfr[i][0], z4, 0,0,0);
        f32x4 m1 = __builtin_amdgcn_mfma_f32_16x16x32_bf16(af[i], bfr[i][1], z4, 0,0,0);
        // D: n=l15=k_out, rows c_off = sg*4+r -> kflat-local byte = k*32 + c_off*2
        char* base = sm.mm + (pl0+i)*1040 + l15*32 + sg*8;
        *(unsigned long long*)(base)       = pack4bf(m0);   // k = l15
        *(unsigned long long*)(base + 512) = pack4bf(m1);   // k = 16+l15
      }
    }
    __syncthreads();
    // ---- stage 2: out[o,p] += OWb[o, kflat] * mm[kflat, p], 16 K-steps this c-block ----
    {
      const unsigned short* arow0 = &OWb[(size_t)(w*32 + l15)*2048 + cblk*512 + sg*8];
      const unsigned short* arow1 = arow0 + 16*2048;
      const char* brow = sm.mm + l15*1040 + sg*16;
      #pragma unroll 4
      for (int tt = 0; tt < 16; ++tt) {
        short8 a0 = *(const short8*)&arow0[tt*32];
        short8 a1 = *(const short8*)&arow1[tt*32];
        short8 bb = *(const short8*)&brow[tt*64];
        acc0 = __builtin_amdgcn_mfma_f32_16x16x32_bf16(a0, bb, acc0, 0,0,0);
        acc1 = __builtin_amdgcn_mfma_f32_16x16x32_bf16(a1, bb, acc1, 0,0,0);
      }
    }
    __syncthreads();
  }

  // ---- epilogue: +bias, BN, f32 store (16 lanes contiguous over p) ----
  #pragma unroll
  for (int mf = 0; mf < 2; ++mf) {
    f32x4 a = mf ? acc1 : acc0;
    #pragma unroll
    for (int r = 0; r < 4; ++r) {
      int o = w*32 + mf*16 + sg*4 + r;
      float sc = og[o] * rsqrtf(ov[o] + 1e-5f);
      float dd = (ob[o] - om[o]) * sc + obeta[o];
      out1[(size_t)(b*128 + o)*NPP + p0 + l15] = a[r] * sc + dd;
    }
  }
}

extern "C" void kernel_launch(void* const* d_in, const int* in_sizes, int n_in,
                              void* d_out, int out_size, void* d_ws, size_t ws_size,
                              hipStream_t stream) {
  (void)in_sizes; (void)n_in; (void)out_size; (void)ws_size;
  const float* new_xyz = (const float*)d_in[0];
  const float* gxyz    = (const float*)d_in[1];
  const float* gfeat   = (const float*)d_in[2];
  const float* whw     = (const float*)d_in[3];
  const float* whb     = (const float*)d_in[4];
  const float* whg     = (const float*)d_in[5];
  const float* whbeta  = (const float*)d_in[6];
  const float* whm     = (const float*)d_in[7];
  const float* whv     = (const float*)d_in[8];
  const float* n1w     = (const float*)d_in[9];
  const float* n1b     = (const float*)d_in[10];
  const float* n1g     = (const float*)d_in[11];
  const float* n1beta  = (const float*)d_in[12];
  const float* n1m     = (const float*)d_in[13];
  const float* n1v     = (const float*)d_in[14];
  const float* n2w     = (const float*)d_in[15];
  const float* n2b     = (const float*)d_in[16];
  const float* n2g     = (const float*)d_in[17];
  const float* n2beta  = (const float*)d_in[18];
  const float* n2m     = (const float*)d_in[19];
  const float* n2v     = (const float*)d_in[20];
  const float* out_w   = (const float*)d_in[21];
  const float* out_b   = (const float*)d_in[22];
  const float* out_g   = (const float*)d_in[23];
  const float* out_bt  = (const float*)d_in[24];
  const float* out_m   = (const float*)d_in[25];
  const float* out_v   = (const float*)d_in[26];

  unsigned short* owb = (unsigned short*)d_ws;   // 512 KB scratch
  float* out0 = (float*)d_out;                   // [16][1024][3] f32
  float* out1 = out0 + 16*1024*3;                // [16][128][1024] f32

  hipLaunchKernelGGL(k_prep, dim3(208), dim3(256), 0, stream, out_w, new_xyz, owb, out0);
  hipLaunchKernelGGL(k_main, dim3(1024), dim3(256), 0, stream,
      gfeat, gxyz, whw, whb, whg, whbeta, whm, whv,
      n1w, n1b, n1g, n1beta, n1m, n1v,
      n2w, n2b, n2g, n2beta, n2m, n2v,
      owb, out_b, out_g, out_bt, out_m, out_v, out1);
}

// Round 4
// 97.449 us; speedup vs baseline: 1.1235x; 1.1235x over previous
//
#include <hip/hip_runtime.h>
#include <hip/hip_bf16.h>

// pointconv fused: density MLP + weight-net + per-point [64x32]x[32x32] + [128x2048] GEMV + BN
// B=16 NP=1024 NS=32 CIN=64 CMID=32 COUT=128. Inputs f32, outputs f32 (bf16 MFMA inside).

#define NPP 1024
#define NSS 32

typedef __attribute__((ext_vector_type(8))) short short8;
typedef __attribute__((ext_vector_type(4))) float f32x4;

__device__ __forceinline__ unsigned short f2bf(float x) {
  union { float f; unsigned u; } v; v.f = x;
  unsigned r = v.u + 0x7FFFu + ((v.u >> 16) & 1u);   // RNE
  return (unsigned short)(r >> 16);
}

__device__ __forceinline__ unsigned long long pack4bf(f32x4 v) {
  return (unsigned long long)f2bf(v[0])
       | ((unsigned long long)f2bf(v[1]) << 16)
       | ((unsigned long long)f2bf(v[2]) << 32)
       | ((unsigned long long)f2bf(v[3]) << 48);
}

// ---- k_prep: OWb[o][kflat] bf16 (kflat = cblk*512 + k*16 + c_off) + output-0 transpose ----
__global__ __launch_bounds__(256) void k_prep(
    const float* __restrict__ out_w, const float* __restrict__ new_xyz,
    unsigned short* __restrict__ owb, float* __restrict__ out0)
{
  int bid = blockIdx.x, t = threadIdx.x;
  if (bid < 16) {
    int gk = bid * 256 + t;            // (o,k): o=gk>>5, k=gk&31 ; 128*32=4096
    int o = gk >> 5, k = gk & 31;
    #pragma unroll
    for (int cb = 0; cb < 4; ++cb) {
      short8 lo, hi;
      #pragma unroll
      for (int c = 0; c < 8; ++c) lo[c] = (short)f2bf(out_w[(o*64 + cb*16 + c)*32 + k]);
      #pragma unroll
      for (int c = 0; c < 8; ++c) hi[c] = (short)f2bf(out_w[(o*64 + cb*16 + 8 + c)*32 + k]);
      *(short8*)&owb[o*2048 + cb*512 + k*16]     = lo;
      *(short8*)&owb[o*2048 + cb*512 + k*16 + 8] = hi;
    }
  } else {
    int idx = (bid - 16) * 256 + t;    // < 49152
    int b = idx / 3072, r = idx - b*3072, p = r / 3, d = r - p*3;
    out0[idx] = new_xyz[(b*3 + d)*NPP + p];
  }
}

// ---- k_main: one wg = (b, 16-point tile), 4 waves ----
// LDS: wd is dead after the bfr hoist -> alias it with a double-buffered mm.
struct Smem {
  union {
    unsigned short wd[16*32*32];   // [p][k][s] bf16 = 32768 B  (wd = w * d2)
    char mm[2][16*1040];           // [buf][p][kflat-local], row = 1024B + 16B pad = 33280 B
  } u;
  float cst[192];                  // folded BN consts
};

__global__ __launch_bounds__(256, 4) void k_main(
    const float* __restrict__ F, const float* __restrict__ GX,
    const float* __restrict__ whw, const float* __restrict__ whb,
    const float* __restrict__ whg, const float* __restrict__ whbeta,
    const float* __restrict__ whm, const float* __restrict__ whv,
    const float* __restrict__ n1w, const float* __restrict__ n1b,
    const float* __restrict__ n1g, const float* __restrict__ n1beta,
    const float* __restrict__ n1m, const float* __restrict__ n1v,
    const float* __restrict__ n2w, const float* __restrict__ n2b,
    const float* __restrict__ n2g, const float* __restrict__ n2beta,
    const float* __restrict__ n2m, const float* __restrict__ n2v,
    const unsigned short* __restrict__ OWb,
    const float* __restrict__ ob, const float* __restrict__ og,
    const float* __restrict__ obeta, const float* __restrict__ om,
    const float* __restrict__ ov,
    float* __restrict__ out1)
{
  __shared__ Smem sm;
  // XCD-aware bijective swizzle (1024 wgs % 8 == 0): one XCD sees contiguous bids.
  int bid = (blockIdx.x & 7) * 128 + (blockIdx.x >> 3);
  int b = bid >> 6, p0 = (bid & 63) << 4;
  int t = threadIdx.x, lane = t & 63, w = t >> 6;
  int l15 = lane & 15, sg = lane >> 4;
  int pl0 = w * 4;

  // ---- prefetch F for cblk 0 (hides HBM latency under phase 0) ----
  const float* fbase = &F[(size_t)((b*64 + l15)*32 + sg*8)*NPP + p0 + pl0];
  float4 av[8];
  #pragma unroll
  for (int j = 0; j < 8; ++j) av[j] = *(const float4*)&fbase[(size_t)j*NPP];

  // ---- phase 0a: gx load (s=0 zeroed per reference mutation), density->inv, max over s ----
  int pp = t >> 4, si = t & 15;        // pp = point 0..15, si -> s = 2si, 2si+1
  float gxl[2][3]; float invv[2];
  #pragma unroll
  for (int u = 0; u < 2; ++u) {
    int s = si*2 + u;
    float x = 0.f, y = 0.f, z = 0.f;
    if (s != 0) {
      const float* g = &GX[(size_t)((b*NPP + p0 + pp)*NSS + s)*3];
      x = g[0]; y = g[1]; z = g[2];
    }
    gxl[u][0]=x; gxl[u][1]=y; gxl[u][2]=z;
    float den = x + y + z;
    if (den < 1e-10f) den = 1e-10f;    // where(density < 1e-10, 1e-10, density)
    invv[u] = 1.0f / den;
  }
  float mx = fmaxf(invv[0], invv[1]);
  #pragma unroll
  for (int m = 1; m < 16; m <<= 1) mx = fmaxf(mx, __shfl_xor(mx, m, 16));

  // folded BN consts
  if (t < 32) {
    float sc = whg[t] * rsqrtf(whv[t] + 1e-5f);
    sm.cst[t]    = whw[t*3+0] * sc;
    sm.cst[32+t] = whw[t*3+1] * sc;
    sm.cst[64+t] = whw[t*3+2] * sc;
    sm.cst[96+t] = (whb[t] - whm[t]) * sc + whbeta[t];
  } else if (t < 48) {
    int i = t - 32;
    float sc = n1g[i] * rsqrtf(n1v[i] + 1e-5f);
    sm.cst[128+i] = n1w[i] * sc;
    sm.cst[144+i] = (n1b[i] - n1m[i]) * sc + n1beta[i];
  } else if (t < 64) {
    int i = t - 48;
    float sc = n2g[0] * rsqrtf(n2v[0] + 1e-5f);
    sm.cst[160+i] = n2w[i] * sc;
    if (i == 0) sm.cst[176] = (n2b[0] - n2m[0]) * sc + n2beta[0];
  }
  __syncthreads();

  // ---- phase 0b: d2 = sigmoid(MLP(ds)), weight-net w, wd = w*d2 -> LDS ----
  float d2v[2];
  #pragma unroll
  for (int u = 0; u < 2; ++u) {
    float ds = invv[u] / mx;
    float acc = sm.cst[176];
    #pragma unroll
    for (int i = 0; i < 16; ++i) {
      float d1 = fmaxf(ds * sm.cst[128+i] + sm.cst[144+i], 0.f);
      acc += d1 * sm.cst[160+i];
    }
    d2v[u] = 1.0f / (1.0f + expf(-acc));
  }
  #pragma unroll 4
  for (int k = 0; k < 32; ++k) {
    float a0 = sm.cst[k], a1 = sm.cst[32+k], a2 = sm.cst[64+k], bc = sm.cst[96+k];
    unsigned r = 0;
    #pragma unroll
    for (int u = 0; u < 2; ++u) {
      float wv = fmaxf(gxl[u][0]*a0 + gxl[u][1]*a1 + gxl[u][2]*a2 + bc, 0.f);
      wv *= d2v[u];
      r |= (unsigned)f2bf(wv) << (16*u);
    }
    *(unsigned*)&sm.u.wd[(pp*32 + k)*32 + si*2] = r;   // [p][k][s], s-pair packed
  }
  __syncthreads();

  // hoisted stage-1 B-frags (wd) for my wave's 4 points: B[k=s][n=k_out]
  short8 bfr[4][2];
  #pragma unroll
  for (int i = 0; i < 4; ++i)
    #pragma unroll
    for (int kh = 0; kh < 2; ++kh)
      bfr[i][kh] = *(const short8*)&sm.u.wd[((pl0+i)*32 + kh*16 + l15)*32 + sg*8];
  __syncthreads();   // wd dead from here; mm buffers may overwrite it

  f32x4 acc0 = {0,0,0,0}, acc1 = {0,0,0,0};
  const f32x4 z4 = {0,0,0,0};

  #pragma unroll
  for (int cblk = 0; cblk < 4; ++cblk) {
    char* mmw = sm.u.mm[cblk & 1];
    // ---- stage 1: pack current av -> af, prefetch next cblk, MFMA, write mm ----
    {
      short8 af[4];
      #pragma unroll
      for (int j = 0; j < 8; ++j) {
        af[0][j] = (short)f2bf(av[j].x);
        af[1][j] = (short)f2bf(av[j].y);
        af[2][j] = (short)f2bf(av[j].z);
        af[3][j] = (short)f2bf(av[j].w);
      }
      if (cblk < 3) {
        const float* src = fbase + (size_t)(cblk + 1) * 16 * 32 * NPP;
        #pragma unroll
        for (int j = 0; j < 8; ++j) av[j] = *(const float4*)&src[(size_t)j*NPP];
      }
      #pragma unroll
      for (int i = 0; i < 4; ++i) {
        f32x4 m0 = __builtin_amdgcn_mfma_f32_16x16x32_bf16(af[i], bfr[i][0], z4, 0,0,0);
        f32x4 m1 = __builtin_amdgcn_mfma_f32_16x16x32_bf16(af[i], bfr[i][1], z4, 0,0,0);
        // D: n=l15=k_out, rows c_off = sg*4+r -> kflat-local byte = k*32 + c_off*2
        char* base = mmw + (pl0+i)*1040 + l15*32 + sg*8;
        *(unsigned long long*)(base)       = pack4bf(m0);   // k = l15
        *(unsigned long long*)(base + 512) = pack4bf(m1);   // k = 16+l15
      }
    }
    __syncthreads();
    // ---- stage 2: out[o,p] += OWb[o, kflat] * mm[kflat, p], 16 K-steps this c-block ----
    // next iteration's stage-1 writes the OTHER mm buffer; reuse of this one is
    // protected by the barrier after that stage-1.
    {
      const unsigned short* arow0 = &OWb[(size_t)(w*32 + l15)*2048 + cblk*512 + sg*8];
      const unsigned short* arow1 = arow0 + 16*2048;
      const char* brow = mmw + l15*1040 + sg*16;
      #pragma unroll 8
      for (int tt = 0; tt < 16; ++tt) {
        short8 a0 = *(const short8*)&arow0[tt*32];
        short8 a1 = *(const short8*)&arow1[tt*32];
        short8 bb = *(const short8*)&brow[tt*64];
        acc0 = __builtin_amdgcn_mfma_f32_16x16x32_bf16(a0, bb, acc0, 0,0,0);
        acc1 = __builtin_amdgcn_mfma_f32_16x16x32_bf16(a1, bb, acc1, 0,0,0);
      }
    }
  }

  // ---- epilogue: +bias, BN, f32 store (16 lanes contiguous over p) ----
  #pragma unroll
  for (int mf = 0; mf < 2; ++mf) {
    f32x4 a = mf ? acc1 : acc0;
    #pragma unroll
    for (int r = 0; r < 4; ++r) {
      int o = w*32 + mf*16 + sg*4 + r;
      float sc = og[o] * rsqrtf(ov[o] + 1e-5f);
      float dd = (ob[o] - om[o]) * sc + obeta[o];
      out1[(size_t)(b*128 + o)*NPP + p0 + l15] = a[r] * sc + dd;
    }
  }
}

extern "C" void kernel_launch(void* const* d_in, const int* in_sizes, int n_in,
                              void* d_out, int out_size, void* d_ws, size_t ws_size,
                              hipStream_t stream) {
  (void)in_sizes; (void)n_in; (void)out_size; (void)ws_size;
  const float* new_xyz = (const float*)d_in[0];
  const float* gxyz    = (const float*)d_in[1];
  const float* gfeat   = (const float*)d_in[2];
  const float* whw     = (const float*)d_in[3];
  const float* whb     = (const float*)d_in[4];
  const float* whg     = (const float*)d_in[5];
  const float* whbeta  = (const float*)d_in[6];
  const float* whm     = (const float*)d_in[7];
  const float* whv     = (const float*)d_in[8];
  const float* n1w     = (const float*)d_in[9];
  const float* n1b     = (const float*)d_in[10];
  const float* n1g     = (const float*)d_in[11];
  const float* n1beta  = (const float*)d_in[12];
  const float* n1m     = (const float*)d_in[13];
  const float* n1v     = (const float*)d_in[14];
  const float* n2w     = (const float*)d_in[15];
  const float* n2b     = (const float*)d_in[16];
  const float* n2g     = (const float*)d_in[17];
  const float* n2beta  = (const float*)d_in[18];
  const float* n2m     = (const float*)d_in[19];
  const float* n2v     = (const float*)d_in[20];
  const float* out_w   = (const float*)d_in[21];
  const float* out_b   = (const float*)d_in[22];
  const float* out_g   = (const float*)d_in[23];
  const float* out_bt  = (const float*)d_in[24];
  const float* out_m   = (const float*)d_in[25];
  const float* out_v   = (const float*)d_in[26];

  unsigned short* owb = (unsigned short*)d_ws;   // 512 KB scratch
  float* out0 = (float*)d_out;                   // [16][1024][3] f32
  float* out1 = out0 + 16*1024*3;                // [16][128][1024] f32

  hipLaunchKernelGGL(k_prep, dim3(208), dim3(256), 0, stream, out_w, new_xyz, owb, out0);
  hipLaunchKernelGGL(k_main, dim3(1024), dim3(256), 0, stream,
      gfeat, gxyz, whw, whb, whg, whbeta, whm, whv,
      n1w, n1b, n1g, n1beta, n1m, n1v,
      n2w, n2b, n2g, n2beta, n2m, n2v,
      owb, out_b, out_g, out_bt, out_m, out_v, out1);
}